// Round 3
// baseline (707.101 us; speedup 1.0000x reference)
//
#include <hip/hip_runtime.h>

// out[B,D] = sum_i k[i] * x[i][B,D]
// x: [6, 16384, 1024] fp32, k: [6] fp32, out: [16384,1024] fp32
//
// R2 DIAGNOSTIC ROUND (intentionally slower): repeat the ENTIRE identical
// workload REPS=4 times inside the kernel. Output is idempotent (same values
// stored each rep) -> still passes. Purpose:
//   1. X = (dur_us_new - 537.9)/3 reveals the kernel's true standalone time,
//      which is currently hidden (suspected fixed ~250-450us of re-poison
//      fills + tiny restore dispatches inside the timed graph).
//   2. 4X >= 300us > the 250us poison fills, so if rocprof attributes
//      graph-launched kernels at all, multidense_kernel MUST now appear in
//      top-5 with its own hbm_gbps / FETCH_SIZE (over-fetch check).
// Pointer laundering (empty inline asm) per rep defeats cross-rep CSE so all
// 4 reps issue real loads/stores.

typedef float vfloat4 __attribute__((ext_vector_type(4)));

#define PLANE_VEC (16384 * 1024 / 4)   // float4 per plane = 4,194,304
#define BLOCKS 2048
#define TPB 256
#define REPS 4

__global__ __launch_bounds__(TPB) void multidense_kernel(
    const vfloat4* __restrict__ x,   // [6 * PLANE_VEC]
    const float*   __restrict__ k,   // [6]
    vfloat4* __restrict__ out) {     // [PLANE_VEC]
    const int stride = BLOCKS * TPB;               // 524288
    const int base = blockIdx.x * TPB + threadIdx.x;

    const float k0 = k[0], k1 = k[1], k2 = k[2], k3 = k[3], k4 = k[4], k5 = k[5];

    const vfloat4* xp = x;
    vfloat4* op = out;

    #pragma unroll 1
    for (int rep = 0; rep < REPS; ++rep) {
        // Opaque barrier: compiler cannot prove xp/op unchanged across reps,
        // so every rep re-issues all loads and stores.
        asm volatile("" : "+v"(xp), "+v"(op));

        int i = base;
        // PLANE_VEC / stride == 8 exactly; unroll 2 -> 4 outer iterations.
        #pragma unroll
        for (int it = 0; it < 4; ++it) {
            const int ia = i;
            const int ib = i + stride;

            vfloat4 a0 = xp[ia + 0 * PLANE_VEC];
            vfloat4 a1 = xp[ia + 1 * PLANE_VEC];
            vfloat4 a2 = xp[ia + 2 * PLANE_VEC];
            vfloat4 a3 = xp[ia + 3 * PLANE_VEC];
            vfloat4 a4 = xp[ia + 4 * PLANE_VEC];
            vfloat4 a5 = xp[ia + 5 * PLANE_VEC];
            vfloat4 b0 = xp[ib + 0 * PLANE_VEC];
            vfloat4 b1 = xp[ib + 1 * PLANE_VEC];
            vfloat4 b2 = xp[ib + 2 * PLANE_VEC];
            vfloat4 b3 = xp[ib + 3 * PLANE_VEC];
            vfloat4 b4 = xp[ib + 4 * PLANE_VEC];
            vfloat4 b5 = xp[ib + 5 * PLANE_VEC];

            vfloat4 ra = k0*a0 + k1*a1 + k2*a2 + k3*a3 + k4*a4 + k5*a5;
            vfloat4 rb = k0*b0 + k1*b1 + k2*b2 + k3*b3 + k4*b4 + k5*b5;

            op[ia] = ra;
            op[ib] = rb;

            i += 2 * stride;
        }
    }
}

extern "C" void kernel_launch(void* const* d_in, const int* in_sizes, int n_in,
                              void* d_out, int out_size, void* d_ws, size_t ws_size,
                              hipStream_t stream) {
    const vfloat4* x = (const vfloat4*)d_in[0];
    const float*   k = (const float*)d_in[1];
    vfloat4* out = (vfloat4*)d_out;

    multidense_kernel<<<BLOCKS, TPB, 0, stream>>>(x, k, out);
}

// Round 4
// 705.405 us; speedup vs baseline: 1.0024x; 1.0024x over previous
//
#include <hip/hip_runtime.h>

// out[B,D] = sum_i k[i] * x[i][B,D]
// x: [6, 16384, 1024] fp32, k: [6] fp32, out: [16384,1024] fp32
//
// R3: RESTRUCTURED ACCESS PATTERN (+ keep REPS=4 diagnostic for counter
// visibility). R3 data: kernel 4-rep dispatch = 321us @ 3.34 TB/s HBM, on top
// of ~386us fixed harness overhead (poison fills + restores) inside the timed
// graph. Cold-rep rate ~3.1 TB/s vs 6.3 TB/s achievable => 2x kernel gap.
//
// Theory: po2 congruent stream camping. Old kernel: every thread issues 6
// loads congruent mod 64 MiB (plane stride) x2 offsets 8 MiB apart + write
// stream = 14 concurrent po2-strided streams -> channel/bank/LLC-slice
// conflicts. Fix: each block owns ONE contiguous 32KB window; iterate planes
// SEQUENTIALLY (register accumulation); rotate plane order by blockIdx%6 so
// blocks spread over all 6 planes at any instant. Concurrent per-thread loads
// now live inside one 32KB region instead of spanning 402MB at po2 strides.
//
// Predict: dispatch 321 -> ~255us (hbm_gbps 3340 -> ~4200) if theory right;
// unchanged if kernel is already request-rate-limited (then next round: REPS
// slope test).

typedef float vfloat4 __attribute__((ext_vector_type(4)));

#define PLANE_VEC (16384 * 1024 / 4)   // 4,194,304 float4 per plane
#define BLOCKS 2048
#define TPB 256
#define PER_THREAD 8                   // PLANE_VEC / (BLOCKS*TPB) == 8 exactly
#define REPS 4

__global__ __launch_bounds__(TPB) void multidense_kernel(
    const vfloat4* __restrict__ x,   // [6 * PLANE_VEC]
    const float*   __restrict__ k,   // [6]
    vfloat4* __restrict__ out) {     // [PLANE_VEC]

    const int tid = threadIdx.x;
    const int b   = blockIdx.x;
    // Block window: contiguous 2048 float4 (32 KB) at b*2048; lane offset tid.
    const int w0  = b * (TPB * PER_THREAD) + tid;
    int b6 = b % 6;                    // start-plane rotation

    const vfloat4* xp = x;
    vfloat4* op = out;

    #pragma unroll 1
    for (int rep = 0; rep < REPS; ++rep) {
        // Opaque: forces all REPS to re-issue loads/stores (no cross-rep CSE).
        asm volatile("" : "+v"(xp), "+v"(op));

        vfloat4 acc[PER_THREAD];
        #pragma unroll
        for (int j = 0; j < PER_THREAD; ++j)
            acc[j] = (vfloat4){0.f, 0.f, 0.f, 0.f};

        // Planes sequentially, order rotated per block.
        #pragma unroll
        for (int pp = 0; pp < 6; ++pp) {
            int p = b6 + pp;
            if (p >= 6) p -= 6;
            const float kp = k[p];                       // block-uniform scalar
            const vfloat4* plane = xp + p * PLANE_VEC + w0;

            vfloat4 v[PER_THREAD];
            #pragma unroll
            for (int j = 0; j < PER_THREAD; ++j)
                v[j] = plane[j * TPB];                   // 8 loads in flight,
            #pragma unroll                               // all within 32 KB
            for (int j = 0; j < PER_THREAD; ++j)
                acc[j] += kp * v[j];
        }

        #pragma unroll
        for (int j = 0; j < PER_THREAD; ++j)
            op[w0 + j * TPB] = acc[j];
    }
}

extern "C" void kernel_launch(void* const* d_in, const int* in_sizes, int n_in,
                              void* d_out, int out_size, void* d_ws, size_t ws_size,
                              hipStream_t stream) {
    const vfloat4* x = (const vfloat4*)d_in[0];
    const float*   k = (const float*)d_in[1];
    vfloat4* out = (vfloat4*)d_out;

    multidense_kernel<<<BLOCKS, TPB, 0, stream>>>(x, k, out);
}

// Round 5
// 669.566 us; speedup vs baseline: 1.0561x; 1.0535x over previous
//
#include <hip/hip_runtime.h>

// out[B,D] = sum_i k[i] * x[i][B,D]
// x: [6, 16384, 1024] fp32, k: [6] fp32, out: [16384,1024] fp32
//
// R5 PROBE: write-elimination on warm reps. Evidence so far: 1-rep kernel
// = 146us (537.9 total - 390us fixed harness resets). Cold read rate 2.76
// TB/s; warm-rep delivered rate 8.4 TB/s (kernel structure not the limit);
// HBM-side rate pinned at 2.7-3.2 TB/s in every regime across two disjoint
// access patterns. Chip reference points: write-only fill = 6.4 TB/s;
// m13 copy "6.29 TB/s" is 1:1 R:W = read 3.15 TB/s. Hypothesis A: achieved
// HBM-READ ceiling ~2.8-3.2 TB/s (intrinsic; MALL fill path) -> 146us is
// the roofline. Hypothesis B: write traffic poisons the read path.
// Discriminator: reps 1-3 do the identical reads but NO stores (acc consumed
// via asm keepalive, rule #17 - verify via FETCH ~786MB). rep 0 writes out
// -> output stays correct.
//   A: dispatch ~300-315us (unchanged), WRITE 262->67MB.
//   B: dispatch ~270-285us -> pursue cooperative read/write phase split.
//   C: dispatch <=265us -> reads exceed 3.5 TB/s without writes; rethink.

typedef float vfloat4 __attribute__((ext_vector_type(4)));

#define PLANE_VEC (16384 * 1024 / 4)   // 4,194,304 float4 per plane
#define BLOCKS 2048
#define TPB 256
#define PER_THREAD 8                   // PLANE_VEC / (BLOCKS*TPB) == 8 exactly
#define REPS 4

__global__ __launch_bounds__(TPB) void multidense_kernel(
    const vfloat4* __restrict__ x,   // [6 * PLANE_VEC]
    const float*   __restrict__ k,   // [6]
    vfloat4* __restrict__ out) {     // [PLANE_VEC]

    const int tid = threadIdx.x;
    const int b   = blockIdx.x;
    const int w0  = b * (TPB * PER_THREAD) + tid;   // contiguous 32KB window
    int b6 = b % 6;                                  // start-plane rotation

    const vfloat4* xp = x;
    vfloat4* op = out;

    #pragma unroll 1
    for (int rep = 0; rep < REPS; ++rep) {
        // Opaque: forces every rep to re-issue all loads (no cross-rep CSE).
        asm volatile("" : "+v"(xp), "+v"(op));

        vfloat4 acc[PER_THREAD];
        #pragma unroll
        for (int j = 0; j < PER_THREAD; ++j)
            acc[j] = (vfloat4){0.f, 0.f, 0.f, 0.f};

        #pragma unroll
        for (int pp = 0; pp < 6; ++pp) {
            int p = b6 + pp;
            if (p >= 6) p -= 6;
            const float kp = k[p];
            const vfloat4* plane = xp + p * PLANE_VEC + w0;

            vfloat4 v[PER_THREAD];
            #pragma unroll
            for (int j = 0; j < PER_THREAD; ++j)
                v[j] = plane[j * TPB];
            #pragma unroll
            for (int j = 0; j < PER_THREAD; ++j)
                acc[j] += kp * v[j];
        }

        if (rep == 0) {
            // Real kernel: cold rep writes the (correct, rep-invariant) output.
            #pragma unroll
            for (int j = 0; j < PER_THREAD; ++j)
                op[w0 + j * TPB] = acc[j];
        } else {
            // READ-ONLY probe reps: consume acc so the loads stay live
            // (rule #17 - ablation-via-skip would DCE the loads; check
            // FETCH_SIZE ~786MB to confirm they survived).
            #pragma unroll
            for (int j = 0; j < PER_THREAD; ++j)
                asm volatile("" :: "v"(acc[j]));
        }
    }
}

extern "C" void kernel_launch(void* const* d_in, const int* in_sizes, int n_in,
                              void* d_out, int out_size, void* d_ws, size_t ws_size,
                              hipStream_t stream) {
    const vfloat4* x = (const vfloat4*)d_in[0];
    const float*   k = (const float*)d_in[1];
    vfloat4* out = (vfloat4*)d_out;

    multidense_kernel<<<BLOCKS, TPB, 0, stream>>>(x, k, out);
}

// Round 6
// 663.817 us; speedup vs baseline: 1.0652x; 1.0087x over previous
//
#include <hip/hip_runtime.h>

// out[B,D] = sum_i k[i] * x[i][B,D]
// x: [6, 16384, 1024] fp32, k: [6] fp32, out: [16384,1024] fp32
//
// R6 PROBE: forced memory-level parallelism. Evidence: HBM read rate pinned
// at 2.76-2.95 TB/s in EVERY regime; VGPR=32-40 in all kernels so far =>
// compiler register-rotates to ~1-2 outstanding loads/thread. Little's law
// puts that exactly at the observed rate. Discriminate "intrinsic ~3.1 TB/s
// read ceiling" vs "MLP limit": issue 12 named loads (2 output slots x 6
// planes), then an empty asm consuming ALL 12 before any FMA -> all 12 must
// be issued, in distinct registers, before the first s_waitcnt. Keep R5 rep
// structure (write rep 0 only; reps 1-3 read-only, acc kept live) for a
// single-variable comparison vs R5's 276.3us dispatch.
//   MLP-limited:    dispatch <=240us, hbm_gbps >=3600, VGPR ~70-90.
//   Intrinsic cap:  dispatch 268-284us -> 146us 1-rep kernel is the read
//                   roofline (403MB/3.15TB/s); revert+declare next round.
//   Validity gate:  VGPR must rise >48, else forcing failed (inconclusive).

typedef float vfloat4 __attribute__((ext_vector_type(4)));

#define PLANE_VEC (16384 * 1024 / 4)   // 4,194,304 float4 per plane
#define BLOCKS 2048
#define TPB 256
#define PER_THREAD 8                   // PLANE_VEC / (BLOCKS*TPB) == 8 exactly
#define REPS 4

__global__ __launch_bounds__(TPB) void multidense_kernel(
    const vfloat4* __restrict__ x,   // [6 * PLANE_VEC]
    const float*   __restrict__ k,   // [6]
    vfloat4* __restrict__ out) {     // [PLANE_VEC]

    const int tid = threadIdx.x;
    const int b   = blockIdx.x;
    const int w0  = b * (TPB * PER_THREAD) + tid;   // contiguous 32KB window

    const float k0 = k[0], k1 = k[1], k2 = k[2], k3 = k[3], k4 = k[4], k5 = k[5];

    const vfloat4* xp = x;
    vfloat4* op = out;

    #pragma unroll 1
    for (int rep = 0; rep < REPS; ++rep) {
        // Opaque: every rep re-issues all loads (no cross-rep CSE).
        asm volatile("" : "+v"(xp), "+v"(op));

        // 4 groups; each group = 2 output slots x 6 planes = 12 loads that
        // are all forced in flight simultaneously.
        #pragma unroll
        for (int g = 0; g < 4; ++g) {
            const int ja = w0 + (2 * g)     * TPB;
            const int jb = w0 + (2 * g + 1) * TPB;

            vfloat4 a0 = xp[ja + 0 * PLANE_VEC];
            vfloat4 a1 = xp[ja + 1 * PLANE_VEC];
            vfloat4 a2 = xp[ja + 2 * PLANE_VEC];
            vfloat4 a3 = xp[ja + 3 * PLANE_VEC];
            vfloat4 a4 = xp[ja + 4 * PLANE_VEC];
            vfloat4 a5 = xp[ja + 5 * PLANE_VEC];
            vfloat4 b0 = xp[jb + 0 * PLANE_VEC];
            vfloat4 b1 = xp[jb + 1 * PLANE_VEC];
            vfloat4 b2 = xp[jb + 2 * PLANE_VEC];
            vfloat4 b3 = xp[jb + 3 * PLANE_VEC];
            vfloat4 b4 = xp[jb + 4 * PLANE_VEC];
            vfloat4 b5 = xp[jb + 5 * PLANE_VEC];

            // MLP fence: all 12 loads must be issued (distinct regs) before
            // the single s_waitcnt this asm forces. No register rotation.
            asm volatile(""
                :: "v"(a0), "v"(a1), "v"(a2), "v"(a3), "v"(a4), "v"(a5),
                   "v"(b0), "v"(b1), "v"(b2), "v"(b3), "v"(b4), "v"(b5));

            vfloat4 ra = k0*a0 + k1*a1 + k2*a2 + k3*a3 + k4*a4 + k5*a5;
            vfloat4 rb = k0*b0 + k1*b1 + k2*b2 + k3*b3 + k4*b4 + k5*b5;

            if (rep == 0) {
                op[ja] = ra;        // correct output written once (rep 0)
                op[jb] = rb;
            } else {
                // keep probe-rep loads live (rule #17)
                asm volatile("" :: "v"(ra), "v"(rb));
            }
        }
    }
}

extern "C" void kernel_launch(void* const* d_in, const int* in_sizes, int n_in,
                              void* d_out, int out_size, void* d_ws, size_t ws_size,
                              hipStream_t stream) {
    const vfloat4* x = (const vfloat4*)d_in[0];
    const float*   k = (const float*)d_in[1];
    vfloat4* out = (vfloat4*)d_out;

    multidense_kernel<<<BLOCKS, TPB, 0, stream>>>(x, k, out);
}